// Round 5
// baseline (819.632 us; speedup 1.0000x reference)
//
#include <hip/hip_runtime.h>
#include <math.h>

#define HH   128
#define H2   256
#define H3   384
#define NPT  65535      // nodes per tree (2^16 - 1)
#define MT   32         // nodes per tile
#define TPB  512        // 8 waves
#define GRID 512        // persistent blocks: 2/CU * 256 CU, co-resident by launch_bounds

typedef __bf16 bf16x8 __attribute__((ext_vector_type(8)));
typedef float  f32x4  __attribute__((ext_vector_type(4)));

__device__ unsigned short Wb_g[640 * 256];   // bf16 [row=output col j][k]; j<384: W_iou, else W_f

__device__ __forceinline__ float fsig(float x)  { return 1.0f / (1.0f + __expf(-x)); }
__device__ __forceinline__ float ftanh(float x) { return 1.0f - 2.0f / (__expf(2.0f * x) + 1.0f); }
__device__ __forceinline__ unsigned short f2bf(float f) {   // RNE fp32->bf16
    unsigned u = __float_as_uint(f);
    u += 0x7fffu + ((u >> 16) & 1u);
    return (unsigned short)(u >> 16);
}

// ---------------- weight convert: fp32 -> bf16, once per launch ----------------
__global__ __launch_bounds__(256) void conv_k(const float* __restrict__ W_iou,
                                              const float* __restrict__ W_f)
{
    int t    = blockIdx.x * 256 + threadIdx.x;
    int base = t * 4;                            // element index into [640][256]
    int j = base >> 8, k = base & 255;
    const float* src = (j < H3) ? (W_iou + (size_t)j * H2 + k)
                                : (W_f + (size_t)(j - H3) * H2 + k);
    float4 v = *(const float4*)src;
    ushort4 p;
    p.x = f2bf(v.x); p.y = f2bf(v.y); p.z = f2bf(v.z); p.w = f2bf(v.w);
    *(ushort4*)(Wb_g + base) = p;
}

// ---------------- leaf frontier: elementwise only ----------------
__global__ __launch_bounds__(256) void leaf_k(
    const float* __restrict__ iou, const float* __restrict__ c_in,
    const float* __restrict__ b_iou,
    float* __restrict__ h_out, float* __restrict__ c_ws,
    unsigned short* __restrict__ h_bf)
{
    int g    = blockIdx.x * 256 + threadIdx.x;
    int node = g >> 5;                           // 131072 leaf nodes
    int e    = (g & 31) << 2;
    int tree = node >> 15;
    int loc  = 32767 + (node & 32767);
    size_t row = (size_t)tree * NPT + loc;

    const float* ip = iou + row * H3;
    float4 vi = *(const float4*)(ip + e);
    float4 vo = *(const float4*)(ip + HH + e);
    float4 vu = *(const float4*)(ip + 2 * HH + e);
    float4 vc = *(const float4*)(c_in + row * HH + e);
    float4 bi = *(const float4*)(b_iou + e);
    float4 bo = *(const float4*)(b_iou + HH + e);
    float4 bu = *(const float4*)(b_iou + 2 * HH + e);

    float4 hn, cn;
#define DO(X) { float iv = fsig(vi.X + bi.X); float ov = fsig(vo.X + bo.X); \
                float uv = ftanh(vu.X + bu.X); float cv = iv * uv + vc.X;   \
                cn.X = cv; hn.X = ov * ftanh(cv); }
    DO(x) DO(y) DO(z) DO(w)
#undef DO
    *(float4*)(h_out + row * HH + e) = hn;
    *(float4*)(c_ws  + row * HH + e) = cn;
    ushort4 hb;
    hb.x = f2bf(hn.x); hb.y = f2bf(hn.y); hb.z = f2bf(hn.z); hb.w = f2bf(hn.w);
    *(ushort4*)(h_bf + row * HH + e) = hb;
}

// ---------------- one 32-node tile: stage -> MFMA -> gates -> writeback ----------------
__device__ __forceinline__ void do_tile(
    int lvl, int tile,
    float bi, float bo, float bu, float bl, float br,
    float* __restrict__ h_g, float* __restrict__ c_ws,
    unsigned short* __restrict__ h_bf,
    unsigned short* A_lds,
    int tid, int w, int lr, int lc, int ee)
{
    const int n_nodes = 4 << lvl;
    const int node0   = tile * MT;
    const int loc0    = (1 << lvl) - 1;
    const int lmask   = loc0;

    __syncthreads();   // prior tile's LDS reads complete before restage

    // ---- stage A = h_cat[32 nodes][256] bf16 into swizzled LDS (reads h_bf) ----
#pragma unroll
    for (int it = 0; it < 2; ++it) {
        int item = tid + TPB * it;         // item over [32 m][32 x 16B-units]
        int m = item >> 5, u = item & 31;
        int node = node0 + m;
        uint4 v = make_uint4(0u, 0u, 0u, 0u);
        if (node < n_nodes) {
            int tree = node >> lvl;
            int loc  = loc0 + (node & lmask);
            size_t crow = (size_t)tree * NPT + 2 * loc + 1 + (u >> 4);
            v = *(const uint4*)(h_bf + crow * HH + (u & 15) * 8);
        }
        int byte = (m * 512 + u * 16) ^ ((m & 7) << 4);
        *(uint4*)((char*)A_lds + byte) = v;
    }
    __syncthreads();

    // ---- MFMA K-loop: acc[mt][gate], 40 f32 regs ----
    f32x4 acc[2][5] = {};
    const unsigned short* Wp = Wb_g + (size_t)(w * 16 + lr) * H2 + lc * 8;

#pragma unroll 2
    for (int kk = 0; kk < 8; ++kk) {
        bf16x8 a0, a1;
        {
            int row = lr;
            int byte = (row * 512 + kk * 64 + lc * 16) ^ ((row & 7) << 4);
            a0 = *(const bf16x8*)((const char*)A_lds + byte);
        }
        {
            int row = 16 + lr;
            int byte = (row * 512 + kk * 64 + lc * 16) ^ ((row & 7) << 4);
            a1 = *(const bf16x8*)((const char*)A_lds + byte);
        }
#pragma unroll
        for (int g = 0; g < 5; ++g) {
            bf16x8 b = *(const bf16x8*)(Wp + (size_t)g * HH * H2 + kk * 32);
            acc[0][g] = __builtin_amdgcn_mfma_f32_16x16x32_bf16(a0, b, acc[0][g], 0, 0, 0);
            acc[1][g] = __builtin_amdgcn_mfma_f32_16x16x32_bf16(a1, b, acc[1][g], 0, 0, 0);
        }
    }

    // ---- epilogue: lane-local gates. C/D: col=lane&15, row=(lane>>4)*4+r ----
#pragma unroll
    for (int mt = 0; mt < 2; ++mt) {
#pragma unroll
        for (int r = 0; r < 4; ++r) {
            int node = node0 + mt * 16 + lc * 4 + r;
            if (node >= n_nodes) continue;
            int tree = node >> lvl;
            int loc  = loc0 + (node & lmask);
            size_t row  = (size_t)tree * NPT + loc;
            size_t lrow = (size_t)tree * NPT + 2 * loc + 1;

            float pi = acc[mt][0][r] + bi;
            float po = acc[mt][1][r] + bo;
            float pu = acc[mt][2][r] + bu;
            float pl = acc[mt][3][r] + bl;
            float pr = acc[mt][4][r] + br;
            float cl = c_ws[lrow * HH + ee];
            float cr = c_ws[(lrow + 1) * HH + ee];
            float cv = fsig(pi) * ftanh(pu) + fsig(pl) * cl + fsig(pr) * cr;
            float hv = fsig(po) * ftanh(cv);
            h_g[row * HH + ee]  = hv;
            c_ws[row * HH + ee] = cv;
            h_bf[row * HH + ee] = f2bf(hv);
        }
    }
}

// ---------------- all 15 internal levels, one persistent launch ----------------
// Phase 1 (l=14..12): subtree-affine, zero inter-block sync.
// Phase 2 (l=11..6): per-tile single-writer/single-reader flags.
// Solo   (l=5..0):   block 0 alone.
// Flag layout: foff(l) = 1024 - (2 << (l-3)), l in [6,12]; 1016 ints total.
__global__ __launch_bounds__(TPB, 4) void tree_k(
    const float* __restrict__ b_iou, const float* __restrict__ b_f,
    float* __restrict__ h_g, float* __restrict__ c_ws,
    unsigned short* __restrict__ h_bf, unsigned int* __restrict__ flags)
{
    __shared__ __align__(16) unsigned short A_lds[MT * H2];   // 16 KB

    const int tid = threadIdx.x;
    const int w   = tid >> 6;
    const int lr  = tid & 15;
    const int lc  = (tid & 63) >> 4;
    const int b   = blockIdx.x;
    const int ee  = w * 16 + lr;
    const float bi = b_iou[ee], bo = b_iou[HH + ee], bu = b_iou[2 * HH + ee];
    const float bl = b_f[ee],   br = b_f[HH + ee];

    // ---- phase 1: l=14 tiles 4b..4b+3, l=13 tiles 2b..2b+1, l=12 tile b ----
#pragma unroll 1
    for (int i = 0; i < 7; ++i) {
        int l = (i < 4) ? 14 : (i < 6) ? 13 : 12;
        int t = (i < 4) ? (4 * b + i) : (i < 6) ? (2 * b + i - 4) : b;
        do_tile(l, t, bi, bo, bu, bl, br, h_g, c_ws, h_bf, A_lds, tid, w, lr, lc, ee);
    }
    __threadfence();
    __syncthreads();
    if (tid == 0)
        __hip_atomic_store(&flags[b], 1u, __ATOMIC_RELEASE, __HIP_MEMORY_SCOPE_AGENT);  // foff(12)=0

    // ---- phase 2: l=11..6, tile b of each, flag-gated ----
#pragma unroll 1
    for (int l = 11; l >= 6; --l) {
        int nt = 1 << (l - 3);
        if (b < nt) {
            int coff = 1024 - (2 << (l - 2));   // foff(l+1)
            if (tid == 0) {
                while (!__hip_atomic_load(&flags[coff + 2 * b],     __ATOMIC_RELAXED, __HIP_MEMORY_SCOPE_AGENT)) {}
                while (!__hip_atomic_load(&flags[coff + 2 * b + 1], __ATOMIC_RELAXED, __HIP_MEMORY_SCOPE_AGENT)) {}
                __builtin_amdgcn_fence(__ATOMIC_ACQUIRE, "agent");
            }
            // do_tile opens with __syncthreads(): other waves wait for the spin
            do_tile(l, b, bi, bo, bu, bl, br, h_g, c_ws, h_bf, A_lds, tid, w, lr, lc, ee);
            __threadfence();
            __syncthreads();
            if (tid == 0)
                __hip_atomic_store(&flags[1024 - (2 << (l - 3)) + b], 1u,
                                   __ATOMIC_RELEASE, __HIP_MEMORY_SCOPE_AGENT);
        }
    }

    // ---- solo tail: block 0 runs l=5..0 (252 nodes), no fences needed ----
    if (b == 0) {
        if (tid < 8) {   // wait all 8 l=6 tiles (foff(6)=1008)
            while (!__hip_atomic_load(&flags[1008 + tid], __ATOMIC_RELAXED, __HIP_MEMORY_SCOPE_AGENT)) {}
        }
        if (tid == 0) __builtin_amdgcn_fence(__ATOMIC_ACQUIRE, "agent");
        const signed char slv[10] = {5,5,5,5,4,4,3,2,1,0};
        const signed char stl[10] = {0,1,2,3,0,1,0,0,0,0};
#pragma unroll 1
        for (int i = 0; i < 10; ++i)
            do_tile(slv[i], stl[i], bi, bo, bu, bl, br, h_g, c_ws, h_bf, A_lds, tid, w, lr, lc, ee);
    }
}

extern "C" void kernel_launch(void* const* d_in, const int* in_sizes, int n_in,
                              void* d_out, int out_size, void* d_ws, size_t ws_size,
                              hipStream_t stream)
{
    const float* iou   = (const float*)d_in[0];
    const float* c_in  = (const float*)d_in[2];
    const float* W_iou = (const float*)d_in[3];
    const float* b_iou = (const float*)d_in[4];
    const float* W_f   = (const float*)d_in[5];
    const float* b_f   = (const float*)d_in[6];
    float* h_out = (float*)d_out;
    float* c_ws  = (float*)d_ws;                                                        // 134 MiB fp32 c
    unsigned short* h_bf = (unsigned short*)((char*)d_ws + (size_t)136 * 1024 * 1024);  // 67 MiB bf16 h
    unsigned int*  flags = (unsigned int*)((char*)d_ws + (size_t)208 * 1024 * 1024);    // 4 KiB flags

    hipMemsetAsync(flags, 0, 4096, stream);
    conv_k<<<160, 256, 0, stream>>>(W_iou, W_f);
    leaf_k<<<16384, 256, 0, stream>>>(iou, c_in, b_iou, h_out, c_ws, h_bf);
    tree_k<<<GRID, TPB, 0, stream>>>(b_iou, b_f, h_out, c_ws, h_bf, flags);
}

// Round 6
// 575.468 us; speedup vs baseline: 1.4243x; 1.4243x over previous
//
#include <hip/hip_runtime.h>
#include <math.h>

#define HH   128
#define H2   256
#define H3   384
#define NPT  65535      // nodes per tree (2^16 - 1)
#define MT   32         // nodes per tile
#define TPB  512        // 8 waves

typedef __bf16 bf16x8 __attribute__((ext_vector_type(8)));
typedef float  f32x4  __attribute__((ext_vector_type(4)));

__device__ unsigned short Wb_g[640 * 256];   // bf16 [row=output col j][k]; j<384: W_iou, else W_f

__device__ __forceinline__ float fsig(float x)  { return 1.0f / (1.0f + __expf(-x)); }
__device__ __forceinline__ float ftanh(float x) { return 1.0f - 2.0f / (__expf(2.0f * x) + 1.0f); }
__device__ __forceinline__ unsigned short f2bf(float f) {   // RNE fp32->bf16
    unsigned u = __float_as_uint(f);
    u += 0x7fffu + ((u >> 16) & 1u);
    return (unsigned short)(u >> 16);
}
__device__ __forceinline__ int swz(int off) { return off ^ (((off >> 9) & 7) << 4); }

// ---------------- weight convert: fp32 -> bf16, once per launch ----------------
__global__ __launch_bounds__(256) void conv_k(const float* __restrict__ W_iou,
                                              const float* __restrict__ W_f)
{
    int t    = blockIdx.x * 256 + threadIdx.x;
    int base = t * 4;
    int j = base >> 8, k = base & 255;
    const float* src = (j < H3) ? (W_iou + (size_t)j * H2 + k)
                                : (W_f + (size_t)(j - H3) * H2 + k);
    float4 v = *(const float4*)src;
    ushort4 p;
    p.x = f2bf(v.x); p.y = f2bf(v.y); p.z = f2bf(v.z); p.w = f2bf(v.w);
    *(ushort4*)(Wb_g + base) = p;
}

// ---------------- leaf frontier: elementwise only ----------------
__global__ __launch_bounds__(256) void leaf_k(
    const float* __restrict__ iou, const float* __restrict__ c_in,
    const float* __restrict__ b_iou,
    float* __restrict__ h_out, float* __restrict__ c_ws,
    unsigned short* __restrict__ h_bf)
{
    int g    = blockIdx.x * 256 + threadIdx.x;
    int node = g >> 5;                           // 131072 leaf nodes
    int e    = (g & 31) << 2;
    int tree = node >> 15;
    int loc  = 32767 + (node & 32767);
    size_t row = (size_t)tree * NPT + loc;

    const float* ip = iou + row * H3;
    float4 vi = *(const float4*)(ip + e);
    float4 vo = *(const float4*)(ip + HH + e);
    float4 vu = *(const float4*)(ip + 2 * HH + e);
    float4 vc = *(const float4*)(c_in + row * HH + e);
    float4 bi = *(const float4*)(b_iou + e);
    float4 bo = *(const float4*)(b_iou + HH + e);
    float4 bu = *(const float4*)(b_iou + 2 * HH + e);

    float4 hn, cn;
#define DO(X) { float iv = fsig(vi.X + bi.X); float ov = fsig(vo.X + bo.X); \
                float uv = ftanh(vu.X + bu.X); float cv = iv * uv + vc.X;   \
                cn.X = cv; hn.X = ov * ftanh(cv); }
    DO(x) DO(y) DO(z) DO(w)
#undef DO
    *(float4*)(h_out + row * HH + e) = hn;
    *(float4*)(c_ws  + row * HH + e) = cn;
    ushort4 hb;
    hb.x = f2bf(hn.x); hb.y = f2bf(hn.y); hb.z = f2bf(hn.z); hb.w = f2bf(hn.w);
    *(ushort4*)(h_bf + row * HH + e) = hb;
}

// ---------------- one 32-node tile (node space spans all trees) ----------------
__device__ __forceinline__ void do_tile(
    int lvl, int tile,
    float bi, float bo, float bu, float bl, float br,
    float* __restrict__ h_g, float* __restrict__ c_ws,
    unsigned short* __restrict__ h_bf,
    unsigned short* A_lds,
    int tid, int w, int lr, int lc, int ee)
{
    const int n_nodes = 4 << lvl;
    const int node0   = tile * MT;
    const int loc0    = (1 << lvl) - 1;
    const int lmask   = loc0;

    __syncthreads();   // prior tile's LDS reads complete before restage

#pragma unroll
    for (int it = 0; it < 2; ++it) {
        int item = tid + TPB * it;
        int m = item >> 5, u = item & 31;
        int node = node0 + m;
        uint4 v = make_uint4(0u, 0u, 0u, 0u);
        if (node < n_nodes) {
            int tree = node >> lvl;
            int loc  = loc0 + (node & lmask);
            size_t crow = (size_t)tree * NPT + 2 * loc + 1 + (u >> 4);
            v = *(const uint4*)(h_bf + crow * HH + (u & 15) * 8);
        }
        *(uint4*)((char*)A_lds + swz(m * 512 + u * 16)) = v;
    }
    __syncthreads();

    f32x4 acc[2][5] = {};
    const unsigned short* Wp = Wb_g + (size_t)(w * 16 + lr) * H2 + lc * 8;

#pragma unroll 2
    for (int kk = 0; kk < 8; ++kk) {
        bf16x8 a0 = *(const bf16x8*)((const char*)A_lds + swz(lr * 512 + kk * 64 + lc * 16));
        bf16x8 a1 = *(const bf16x8*)((const char*)A_lds + swz((16 + lr) * 512 + kk * 64 + lc * 16));
#pragma unroll
        for (int g = 0; g < 5; ++g) {
            bf16x8 b = *(const bf16x8*)(Wp + (size_t)g * HH * H2 + kk * 32);
            acc[0][g] = __builtin_amdgcn_mfma_f32_16x16x32_bf16(a0, b, acc[0][g], 0, 0, 0);
            acc[1][g] = __builtin_amdgcn_mfma_f32_16x16x32_bf16(a1, b, acc[1][g], 0, 0, 0);
        }
    }

#pragma unroll
    for (int mt = 0; mt < 2; ++mt) {
#pragma unroll
        for (int r = 0; r < 4; ++r) {
            int node = node0 + mt * 16 + lc * 4 + r;
            if (node >= n_nodes) continue;
            int tree = node >> lvl;
            int loc  = loc0 + (node & lmask);
            size_t row  = (size_t)tree * NPT + loc;
            size_t lrow = (size_t)tree * NPT + 2 * loc + 1;

            float pi = acc[mt][0][r] + bi;
            float po = acc[mt][1][r] + bo;
            float pu = acc[mt][2][r] + bu;
            float pl = acc[mt][3][r] + bl;
            float pr = acc[mt][4][r] + br;
            float cl = c_ws[lrow * HH + ee];
            float cr = c_ws[(lrow + 1) * HH + ee];
            float cv = fsig(pi) * ftanh(pu) + fsig(pl) * cl + fsig(pr) * cr;
            float hv = fsig(po) * ftanh(cv);
            h_g[row * HH + ee]  = hv;
            c_ws[row * HH + ee] = cv;
            h_bf[row * HH + ee] = f2bf(hv);
        }
    }
}

// ---------------- single level (l=11..9) ----------------
__global__ __launch_bounds__(TPB, 4) void level_k(
    int lvl,
    const float* __restrict__ b_iou, const float* __restrict__ b_f,
    float* __restrict__ h_g, float* __restrict__ c_ws,
    unsigned short* __restrict__ h_bf)
{
    __shared__ __align__(16) unsigned short A_lds[MT * H2];
    const int tid = threadIdx.x;
    const int w = tid >> 6, lr = tid & 15, lc = (tid & 63) >> 4;
    const int ee = w * 16 + lr;
    const float bi = b_iou[ee], bo = b_iou[HH + ee], bu = b_iou[2 * HH + ee];
    const float bl = b_f[ee],   br = b_f[HH + ee];
    do_tile(lvl, blockIdx.x, bi, bo, bu, bl, br, h_g, c_ws, h_bf, A_lds, tid, w, lr, lc, ee);
}

// ---------------- fused l=14,13,12: subtree-affine, fence-free ----------------
__global__ __launch_bounds__(TPB, 4) void fuse3_k(
    const float* __restrict__ b_iou, const float* __restrict__ b_f,
    float* __restrict__ h_g, float* __restrict__ c_ws,
    unsigned short* __restrict__ h_bf)
{
    __shared__ __align__(16) unsigned short A_lds[MT * H2];
    const int tid = threadIdx.x;
    const int w = tid >> 6, lr = tid & 15, lc = (tid & 63) >> 4;
    const int ee = w * 16 + lr;
    const int b  = blockIdx.x;
    const float bi = b_iou[ee], bo = b_iou[HH + ee], bu = b_iou[2 * HH + ee];
    const float bl = b_f[ee],   br = b_f[HH + ee];

#pragma unroll 1
    for (int i = 0; i < 7; ++i) {
        int l = (i < 4) ? 14 : (i < 6) ? 13 : 12;
        int t = (i < 4) ? (4 * b + i) : (i < 6) ? (2 * b + i - 4) : b;
        do_tile(l, t, bi, bo, bu, bl, br, h_g, c_ws, h_bf, A_lds, tid, w, lr, lc, ee);
    }
}

// ---------------- tail l=8..0: one block per tree, LDS-resident h chain ----------------
// LDS: bufA [0,32K) holds l=7 (and l=5,3,1) outputs; bufB=[32K,48K) aliases
// A_lds during l=8/7 staging, then holds l=6,4,2,0 outputs.
__global__ __launch_bounds__(TPB, 2) void tail_k(
    const float* __restrict__ b_iou, const float* __restrict__ b_f,
    float* __restrict__ h_g, float* __restrict__ c_ws,
    unsigned short* __restrict__ h_bf)
{
    __shared__ __align__(16) unsigned char hb[49152];

    const int tid = threadIdx.x;
    const int w = tid >> 6, lr = tid & 15, lc = (tid & 63) >> 4;
    const int ee = w * 16 + lr;
    const size_t tb = (size_t)blockIdx.x * NPT;
    const float bi = b_iou[ee], bo = b_iou[HH + ee], bu = b_iou[2 * HH + ee];
    const float bl = b_f[ee],   br = b_f[HH + ee];
    unsigned short* A_lds = (unsigned short*)(hb + 32768);
    const unsigned short* Wp = Wb_g + (size_t)(w * 16 + lr) * H2 + lc * 8;

    // ---- l=8 (8 tiles) + l=7 (4 tiles): children from global h_bf ----
#pragma unroll 1
    for (int i = 0; i < 12; ++i) {
        const int l     = (i < 8) ? 8 : 7;
        const int tile  = (i < 8) ? i : (i - 8);
        const int loc0  = (1 << l) - 1;
        const int cloc0 = 2 * loc0 + 1;

        __syncthreads();
#pragma unroll
        for (int it = 0; it < 2; ++it) {
            int item = tid + TPB * it;
            int m = item >> 5, u = item & 31;
            int j = tile * 32 + m;
            size_t crow = tb + cloc0 + 2 * j + (u >> 4);
            uint4 v = *(const uint4*)(h_bf + crow * HH + (u & 15) * 8);
            *(uint4*)((char*)A_lds + swz(m * 512 + u * 16)) = v;
        }
        __syncthreads();

        f32x4 acc[2][5] = {};
#pragma unroll 2
        for (int kk = 0; kk < 8; ++kk) {
            bf16x8 a0 = *(const bf16x8*)((const char*)A_lds + swz(lr * 512 + kk * 64 + lc * 16));
            bf16x8 a1 = *(const bf16x8*)((const char*)A_lds + swz((16 + lr) * 512 + kk * 64 + lc * 16));
#pragma unroll
            for (int g = 0; g < 5; ++g) {
                bf16x8 bb = *(const bf16x8*)(Wp + (size_t)g * HH * H2 + kk * 32);
                acc[0][g] = __builtin_amdgcn_mfma_f32_16x16x32_bf16(a0, bb, acc[0][g], 0, 0, 0);
                acc[1][g] = __builtin_amdgcn_mfma_f32_16x16x32_bf16(a1, bb, acc[1][g], 0, 0, 0);
            }
        }
#pragma unroll
        for (int mt = 0; mt < 2; ++mt) {
#pragma unroll
            for (int r = 0; r < 4; ++r) {
                int j = tile * 32 + mt * 16 + lc * 4 + r;
                size_t row  = tb + loc0 + j;
                size_t lrow = tb + cloc0 + 2 * j;
                float pi = acc[mt][0][r] + bi;
                float po = acc[mt][1][r] + bo;
                float pu = acc[mt][2][r] + bu;
                float pl = acc[mt][3][r] + bl;
                float pr = acc[mt][4][r] + br;
                float cl = c_ws[lrow * HH + ee];
                float cr = c_ws[(lrow + 1) * HH + ee];
                float cv = fsig(pi) * ftanh(pu) + fsig(pl) * cl + fsig(pr) * cr;
                float hv = fsig(po) * ftanh(cv);
                h_g[row * HH + ee]  = hv;
                c_ws[row * HH + ee] = cv;
                if (l == 8) h_bf[row * HH + ee] = f2bf(hv);
                else *(unsigned short*)(hb + swz(j * 256 + ee * 2)) = f2bf(hv);  // l=7 -> bufA
            }
        }
    }

    // ---- l=6..0: children resident in LDS ----
#pragma unroll 1
    for (int l = 6; l >= 0; --l) {
        __syncthreads();
        const int nl     = 1 << l;
        const int loc0   = nl - 1;
        const int cloc0  = 2 * nl - 1;
        const int cbase  = (l & 1) ? 32768 : 0;   // = obase(l+1)
        const int obase  = (l & 1) ? 0 : 32768;
        const int ntiles = (nl + 31) >> 5;

#pragma unroll 1
        for (int tile = 0; tile < ntiles; ++tile) {
            f32x4 acc[2][5] = {};
#pragma unroll 2
            for (int kk = 0; kk < 8; ++kk) {
                int j0 = tile * 32 + lr;
                bf16x8 a0 = *(const bf16x8*)((const char*)hb + cbase + swz(j0 * 512 + kk * 64 + lc * 16));
                bf16x8 a1 = *(const bf16x8*)((const char*)hb + cbase + swz((j0 + 16) * 512 + kk * 64 + lc * 16));
#pragma unroll
                for (int g = 0; g < 5; ++g) {
                    bf16x8 bb = *(const bf16x8*)(Wp + (size_t)g * HH * H2 + kk * 32);
                    acc[0][g] = __builtin_amdgcn_mfma_f32_16x16x32_bf16(a0, bb, acc[0][g], 0, 0, 0);
                    acc[1][g] = __builtin_amdgcn_mfma_f32_16x16x32_bf16(a1, bb, acc[1][g], 0, 0, 0);
                }
            }
#pragma unroll
            for (int mt = 0; mt < 2; ++mt) {
#pragma unroll
                for (int r = 0; r < 4; ++r) {
                    int j = tile * 32 + mt * 16 + lc * 4 + r;
                    if (j >= nl) continue;
                    size_t row  = tb + loc0 + j;
                    size_t lrow = tb + cloc0 + 2 * j;
                    float pi = acc[mt][0][r] + bi;
                    float po = acc[mt][1][r] + bo;
                    float pu = acc[mt][2][r] + bu;
                    float pl = acc[mt][3][r] + bl;
                    float pr = acc[mt][4][r] + br;
                    float cl = c_ws[lrow * HH + ee];
                    float cr = c_ws[(lrow + 1) * HH + ee];
                    float cv = fsig(pi) * ftanh(pu) + fsig(pl) * cl + fsig(pr) * cr;
                    float hv = fsig(po) * ftanh(cv);
                    h_g[row * HH + ee]  = hv;
                    c_ws[row * HH + ee] = cv;
                    *(unsigned short*)(hb + obase + swz(j * 256 + ee * 2)) = f2bf(hv);
                }
            }
        }
    }
}

extern "C" void kernel_launch(void* const* d_in, const int* in_sizes, int n_in,
                              void* d_out, int out_size, void* d_ws, size_t ws_size,
                              hipStream_t stream)
{
    const float* iou   = (const float*)d_in[0];
    const float* c_in  = (const float*)d_in[2];
    const float* W_iou = (const float*)d_in[3];
    const float* b_iou = (const float*)d_in[4];
    const float* W_f   = (const float*)d_in[5];
    const float* b_f   = (const float*)d_in[6];
    float* h_out = (float*)d_out;
    float* c_ws  = (float*)d_ws;                                                        // 134 MiB fp32 c
    unsigned short* h_bf = (unsigned short*)((char*)d_ws + (size_t)136 * 1024 * 1024);  // 67 MiB bf16 h

    conv_k<<<160, 256, 0, stream>>>(W_iou, W_f);
    leaf_k<<<16384, 256, 0, stream>>>(iou, c_in, b_iou, h_out, c_ws, h_bf);

    fuse3_k<<<512, TPB, 0, stream>>>(b_iou, b_f, h_out, c_ws, h_bf);          // l=14,13,12
    for (int l = 11; l >= 9; --l) {
        int blocks = (4 << l) / MT;
        level_k<<<blocks, TPB, 0, stream>>>(l, b_iou, b_f, h_out, c_ws, h_bf);
    }
    tail_k<<<4, TPB, 0, stream>>>(b_iou, b_f, h_out, c_ws, h_bf);             // l=8..0
}

// Round 7
// 385.244 us; speedup vs baseline: 2.1276x; 1.4938x over previous
//
#include <hip/hip_runtime.h>
#include <math.h>

#define HH   128
#define H2   256
#define H3   384
#define NPT  65535      // nodes per tree (2^16 - 1)
#define MT   32         // nodes per tile
#define TPB  512        // 8 waves

typedef __bf16 bf16x8 __attribute__((ext_vector_type(8)));
typedef float  f32x4  __attribute__((ext_vector_type(4)));

__device__ unsigned short Wb_g[640 * 256];   // bf16 [row=output col j][k]; j<384: W_iou, else W_f

__device__ __forceinline__ float fsig(float x)  { return 1.0f / (1.0f + __expf(-x)); }
__device__ __forceinline__ float ftanh(float x) { return 1.0f - 2.0f / (__expf(2.0f * x) + 1.0f); }
__device__ __forceinline__ unsigned short f2bf(float f) {   // RNE fp32->bf16
    unsigned u = __float_as_uint(f);
    u += 0x7fffu + ((u >> 16) & 1u);
    return (unsigned short)(u >> 16);
}
__device__ __forceinline__ int swz(int off) { return off ^ (((off >> 9) & 7) << 4); }

// ---------------- weight convert: fp32 -> bf16, once per launch ----------------
__global__ __launch_bounds__(256) void conv_k(const float* __restrict__ W_iou,
                                              const float* __restrict__ W_f)
{
    int t    = blockIdx.x * 256 + threadIdx.x;
    int base = t * 4;
    int j = base >> 8, k = base & 255;
    const float* src = (j < H3) ? (W_iou + (size_t)j * H2 + k)
                                : (W_f + (size_t)(j - H3) * H2 + k);
    float4 v = *(const float4*)src;
    ushort4 p;
    p.x = f2bf(v.x); p.y = f2bf(v.y); p.z = f2bf(v.z); p.w = f2bf(v.w);
    *(ushort4*)(Wb_g + base) = p;
}

// ---------------- leaf frontier: elementwise only ----------------
__global__ __launch_bounds__(256) void leaf_k(
    const float* __restrict__ iou, const float* __restrict__ c_in,
    const float* __restrict__ b_iou,
    float* __restrict__ h_out, float* __restrict__ c_ws,
    unsigned short* __restrict__ h_bf)
{
    int g    = blockIdx.x * 256 + threadIdx.x;
    int node = g >> 5;                           // 131072 leaf nodes
    int e    = (g & 31) << 2;
    int tree = node >> 15;
    int loc  = 32767 + (node & 32767);
    size_t row = (size_t)tree * NPT + loc;

    const float* ip = iou + row * H3;
    float4 vi = *(const float4*)(ip + e);
    float4 vo = *(const float4*)(ip + HH + e);
    float4 vu = *(const float4*)(ip + 2 * HH + e);
    float4 vc = *(const float4*)(c_in + row * HH + e);
    float4 bi = *(const float4*)(b_iou + e);
    float4 bo = *(const float4*)(b_iou + HH + e);
    float4 bu = *(const float4*)(b_iou + 2 * HH + e);

    float4 hn, cn;
#define DO(X) { float iv = fsig(vi.X + bi.X); float ov = fsig(vo.X + bo.X); \
                float uv = ftanh(vu.X + bu.X); float cv = iv * uv + vc.X;   \
                cn.X = cv; hn.X = ov * ftanh(cv); }
    DO(x) DO(y) DO(z) DO(w)
#undef DO
    *(float4*)(h_out + row * HH + e) = hn;
    *(float4*)(c_ws  + row * HH + e) = cn;
    ushort4 hb;
    hb.x = f2bf(hn.x); hb.y = f2bf(hn.y); hb.z = f2bf(hn.z); hb.w = f2bf(hn.w);
    *(ushort4*)(h_bf + row * HH + e) = hb;
}

// ---------------- one 32-node tile, l>=6 (node counts exact multiples of 32) ----------------
__device__ __forceinline__ void do_tile(
    int lvl, int tile,
    float bi, float bo, float bu, float bl, float br,
    float* __restrict__ h_g, float* __restrict__ c_ws,
    unsigned short* __restrict__ h_bf,
    unsigned short* A_lds,
    int tid, int w, int lr, int lc, int ee)
{
    const int node0 = tile * MT;
    const int loc0  = (1 << lvl) - 1;
    const int lmask = loc0;

    __syncthreads();   // prior tile's LDS reads complete before restage

#pragma unroll
    for (int it = 0; it < 2; ++it) {
        int item = tid + TPB * it;
        int m = item >> 5, u = item & 31;
        int node = node0 + m;
        int tree = node >> lvl;
        int loc  = loc0 + (node & lmask);
        size_t crow = (size_t)tree * NPT + 2 * loc + 1 + (u >> 4);
        uint4 v = *(const uint4*)(h_bf + crow * HH + (u & 15) * 8);
        *(uint4*)((char*)A_lds + swz(m * 512 + u * 16)) = v;
    }
    __syncthreads();

    f32x4 acc[2][5] = {};
    const unsigned short* Wp = Wb_g + (size_t)(w * 16 + lr) * H2 + lc * 8;

#pragma unroll 4
    for (int kk = 0; kk < 8; ++kk) {
        bf16x8 a0 = *(const bf16x8*)((const char*)A_lds + swz(lr * 512 + kk * 64 + lc * 16));
        bf16x8 a1 = *(const bf16x8*)((const char*)A_lds + swz((16 + lr) * 512 + kk * 64 + lc * 16));
#pragma unroll
        for (int g = 0; g < 5; ++g) {
            bf16x8 b = *(const bf16x8*)(Wp + (size_t)g * HH * H2 + kk * 32);
            acc[0][g] = __builtin_amdgcn_mfma_f32_16x16x32_bf16(a0, b, acc[0][g], 0, 0, 0);
            acc[1][g] = __builtin_amdgcn_mfma_f32_16x16x32_bf16(a1, b, acc[1][g], 0, 0, 0);
        }
    }

    // ---- batched child-c loads: all 16 in flight before any use ----
    float clv[2][4], crv[2][4];
#pragma unroll
    for (int mt = 0; mt < 2; ++mt) {
#pragma unroll
        for (int r = 0; r < 4; ++r) {
            int node = node0 + mt * 16 + lc * 4 + r;
            int tree = node >> lvl;
            int loc  = loc0 + (node & lmask);
            size_t lrow = (size_t)tree * NPT + 2 * loc + 1;
            clv[mt][r] = c_ws[lrow * HH + ee];
            crv[mt][r] = c_ws[(lrow + 1) * HH + ee];
        }
    }

#pragma unroll
    for (int mt = 0; mt < 2; ++mt) {
#pragma unroll
        for (int r = 0; r < 4; ++r) {
            int node = node0 + mt * 16 + lc * 4 + r;
            int tree = node >> lvl;
            int loc  = loc0 + (node & lmask);
            size_t row = (size_t)tree * NPT + loc;

            float pi = acc[mt][0][r] + bi;
            float po = acc[mt][1][r] + bo;
            float pu = acc[mt][2][r] + bu;
            float pl = acc[mt][3][r] + bl;
            float pr = acc[mt][4][r] + br;
            float cv = fsig(pi) * ftanh(pu) + fsig(pl) * clv[mt][r] + fsig(pr) * crv[mt][r];
            float hv = fsig(po) * ftanh(cv);
            h_g[row * HH + ee]  = hv;
            c_ws[row * HH + ee] = cv;
            h_bf[row * HH + ee] = f2bf(hv);
        }
    }
}

// ---------------- single level (l=11..6) ----------------
__global__ __launch_bounds__(TPB, 4) void level_k(
    int lvl,
    const float* __restrict__ b_iou, const float* __restrict__ b_f,
    float* __restrict__ h_g, float* __restrict__ c_ws,
    unsigned short* __restrict__ h_bf)
{
    __shared__ __align__(16) unsigned short A_lds[MT * H2];
    const int tid = threadIdx.x;
    const int w = tid >> 6, lr = tid & 15, lc = (tid & 63) >> 4;
    const int ee = w * 16 + lr;
    const float bi = b_iou[ee], bo = b_iou[HH + ee], bu = b_iou[2 * HH + ee];
    const float bl = b_f[ee],   br = b_f[HH + ee];
    do_tile(lvl, blockIdx.x, bi, bo, bu, bl, br, h_g, c_ws, h_bf, A_lds, tid, w, lr, lc, ee);
}

// ---------------- fused l=14,13,12: subtree-affine, fence-free ----------------
__global__ __launch_bounds__(TPB, 4) void fuse3_k(
    const float* __restrict__ b_iou, const float* __restrict__ b_f,
    float* __restrict__ h_g, float* __restrict__ c_ws,
    unsigned short* __restrict__ h_bf)
{
    __shared__ __align__(16) unsigned short A_lds[MT * H2];
    const int tid = threadIdx.x;
    const int w = tid >> 6, lr = tid & 15, lc = (tid & 63) >> 4;
    const int ee = w * 16 + lr;
    const int b  = blockIdx.x;
    const float bi = b_iou[ee], bo = b_iou[HH + ee], bu = b_iou[2 * HH + ee];
    const float bl = b_f[ee],   br = b_f[HH + ee];

#pragma unroll 1
    for (int i = 0; i < 7; ++i) {
        int l = (i < 4) ? 14 : (i < 6) ? 13 : 12;
        int t = (i < 4) ? (4 * b + i) : (i < 6) ? (2 * b + i - 4) : b;
        do_tile(l, t, bi, bo, bu, bl, br, h_g, c_ws, h_bf, A_lds, tid, w, lr, lc, ee);
    }
}

// ---------------- solo tail l=5..0: one block per tree, weights in registers ----------------
// Children h LDS-resident ping-pong (two 16 KB buffers). Per-tile inner loop is
// pure ds_read + MFMA; only global traffic is 16 L2-hot c loads + output stores.
__global__ __launch_bounds__(TPB, 2) void solo_k(
    const float* __restrict__ b_iou, const float* __restrict__ b_f,
    float* __restrict__ h_g, float* __restrict__ c_ws,
    const unsigned short* __restrict__ h_bf)
{
    __shared__ __align__(16) unsigned char hb[32768];

    const int tid = threadIdx.x;
    const int w = tid >> 6, lr = tid & 15, lc = (tid & 63) >> 4;
    const int ee = w * 16 + lr;
    const size_t tb = (size_t)blockIdx.x * NPT;
    const float bi = b_iou[ee], bo = b_iou[HH + ee], bu = b_iou[2 * HH + ee];
    const float bl = b_f[ee],   br = b_f[HH + ee];

    // hoist ALL 40 weight fragments into registers (160 VGPRs)
    bf16x8 Bf[5][8];
    const unsigned short* Wp = Wb_g + (size_t)(w * 16 + lr) * H2 + lc * 8;
#pragma unroll
    for (int g = 0; g < 5; ++g)
#pragma unroll
        for (int kk = 0; kk < 8; ++kk)
            Bf[g][kk] = *(const bf16x8*)(Wp + (size_t)g * HH * H2 + kk * 32);

    // stage l=6 h (64 nodes x 256B = 16 KB) into bufA
#pragma unroll
    for (int it = 0; it < 2; ++it) {
        int p = tid + TPB * it;            // 1024 chunks of 16B
        int cc = p >> 4, q = p & 15;
        uint4 v = *(const uint4*)(h_bf + (tb + 63 + cc) * HH + q * 8);
        *(uint4*)(hb + swz(p * 16)) = v;
    }

#pragma unroll 1
    for (int l = 5; l >= 0; --l) {
        const int nl     = 1 << l;
        const int loc0   = nl - 1;
        const int cloc0  = 2 * nl - 1;
        const int cbase  = (l & 1) ? 0 : 16384;   // l=5 reads bufA(0), alternate after
        const int obase  = cbase ^ 16384;
        const bool mt1   = (nl > 16);

        __syncthreads();   // prior epilogue's LDS writes visible; prior reads of obase done

        f32x4 acc[2][5] = {};
#pragma unroll
        for (int kk = 0; kk < 8; ++kk) {
            bf16x8 a0 = *(const bf16x8*)(hb + cbase + swz(lr * 512 + kk * 64 + lc * 16));
#pragma unroll
            for (int g = 0; g < 5; ++g)
                acc[0][g] = __builtin_amdgcn_mfma_f32_16x16x32_bf16(a0, Bf[g][kk], acc[0][g], 0, 0, 0);
            if (mt1) {
                bf16x8 a1 = *(const bf16x8*)(hb + cbase + swz((16 + lr) * 512 + kk * 64 + lc * 16));
#pragma unroll
                for (int g = 0; g < 5; ++g)
                    acc[1][g] = __builtin_amdgcn_mfma_f32_16x16x32_bf16(a1, Bf[g][kk], acc[1][g], 0, 0, 0);
            }
        }
        __syncthreads();   // kk reads of cbase done before epilogue overwrites obase

#pragma unroll
        for (int mt = 0; mt < 2; ++mt) {
#pragma unroll
            for (int r = 0; r < 4; ++r) {
                int j = mt * 16 + lc * 4 + r;
                if (j >= nl) continue;
                size_t row  = tb + loc0 + j;
                size_t lrow = tb + cloc0 + 2 * j;
                float pi = acc[mt][0][r] + bi;
                float po = acc[mt][1][r] + bo;
                float pu = acc[mt][2][r] + bu;
                float pl = acc[mt][3][r] + bl;
                float pr = acc[mt][4][r] + br;
                float cv = fsig(pi) * ftanh(pu) + fsig(pl) * c_ws[lrow * HH + ee]
                                                + fsig(pr) * c_ws[(lrow + 1) * HH + ee];
                float hv = fsig(po) * ftanh(cv);
                h_g[row * HH + ee]  = hv;
                c_ws[row * HH + ee] = cv;
                *(unsigned short*)(hb + obase + swz(j * 256 + ee * 2)) = f2bf(hv);
            }
        }
    }
}

extern "C" void kernel_launch(void* const* d_in, const int* in_sizes, int n_in,
                              void* d_out, int out_size, void* d_ws, size_t ws_size,
                              hipStream_t stream)
{
    const float* iou   = (const float*)d_in[0];
    const float* c_in  = (const float*)d_in[2];
    const float* W_iou = (const float*)d_in[3];
    const float* b_iou = (const float*)d_in[4];
    const float* W_f   = (const float*)d_in[5];
    const float* b_f   = (const float*)d_in[6];
    float* h_out = (float*)d_out;
    float* c_ws  = (float*)d_ws;                                                        // 134 MiB fp32 c
    unsigned short* h_bf = (unsigned short*)((char*)d_ws + (size_t)136 * 1024 * 1024);  // 67 MiB bf16 h

    conv_k<<<160, 256, 0, stream>>>(W_iou, W_f);
    leaf_k<<<16384, 256, 0, stream>>>(iou, c_in, b_iou, h_out, c_ws, h_bf);

    fuse3_k<<<512, TPB, 0, stream>>>(b_iou, b_f, h_out, c_ws, h_bf);          // l=14,13,12
    for (int l = 11; l >= 6; --l) {
        int blocks = (4 << l) / MT;
        level_k<<<blocks, TPB, 0, stream>>>(l, b_iou, b_f, h_out, c_ws, h_bf);
    }
    solo_k<<<4, TPB, 0, stream>>>(b_iou, b_f, h_out, c_ws, h_bf);             // l=5..0
}